// Round 9
// baseline (6209.856 us; speedup 1.0000x reference)
//
#include <hip/hip_runtime.h>

#define MDIM 128
#define NCOL 20000
#define NEDGE 320000
#define NITER 30
#define NBLK 625
#define FKAPPA 0.99f

typedef unsigned int uint;
typedef unsigned short ushort;
typedef __attribute__((ext_vector_type(8))) short short8;
typedef __attribute__((ext_vector_type(4))) float f32x4;

__device__ __forceinline__ float bf2f(ushort b){
    uint u = ((uint)b) << 16;
    return __builtin_bit_cast(float, u);
}
__device__ __forceinline__ ushort f2bf(float f){
    uint u = __builtin_bit_cast(uint, f);
    uint r = (u + 0x7fffu + ((u >> 16) & 1u)) >> 16;
    return (ushort)r;
}

// ---------------- CSC build ----------------
__global__ void k_zero(int* __restrict__ p, int* __restrict__ bar){
    int i = blockIdx.x * 256 + threadIdx.x;
    if (i < 2 * NCOL) p[i] = 0;
    if (i < 2) bar[i] = 0;
}

__global__ void k_hist(const int* __restrict__ cols, int* __restrict__ cnt){
    int e = blockIdx.x * 256 + threadIdx.x;
    if (e < NEDGE) atomicAdd(&cnt[cols[e]], 1);
}

__global__ void k_scan(const int* __restrict__ cnt, int* __restrict__ start){
    __shared__ int lds[256];
    const int SEG = (NCOL + 255) / 256; // 79
    int t = threadIdx.x;
    int lo = t * SEG;
    int hi = min(lo + SEG, NCOL);
    int s = 0;
    for (int i = lo; i < hi; ++i) s += cnt[i];
    lds[t] = s;
    __syncthreads();
    for (int off = 1; off < 256; off <<= 1){
        int v = (t >= off) ? lds[t - off] : 0;
        __syncthreads();
        lds[t] += v;
        __syncthreads();
    }
    int run = (t > 0) ? lds[t - 1] : 0;
    for (int i = lo; i < hi; ++i){ start[i] = run; run += cnt[i]; }
    if (hi == NCOL && lo < NCOL) start[NCOL] = run;
}

// edges[p] = { row, f32_bits(val) }
__global__ void k_scatter(const int* __restrict__ rows, const int* __restrict__ cols,
                          const float* __restrict__ vals, const int* __restrict__ start,
                          int* __restrict__ cursor, uint2* __restrict__ edges){
    int e = blockIdx.x * 256 + threadIdx.x;
    if (e < NEDGE){
        int c = cols[e];
        int p = start[c] + atomicAdd(&cursor[c], 1);
        edges[p] = make_uint2((uint)rows[e], __builtin_bit_cast(uint, vals[e]));
    }
}

// ---------------- L-inf projection of W ----------------
__global__ void k_project(const float* __restrict__ W, ushort* __restrict__ Wp){
    int row = blockIdx.x * 4 + (threadIdx.x >> 6);
    int l = threadIdx.x & 63;
    const float* wr = W + row * MDIM;
    float w0 = wr[l], w1 = wr[l + 64];
    float a0 = fabsf(w0), a1 = fabsf(w1);
    float s = a0 + a1, mx = fmaxf(a0, a1);
    for (int off = 32; off; off >>= 1){
        s += __shfl_xor(s, off);
        mx = fmaxf(mx, __shfl_xor(mx, off));
    }
    if (s > FKAPPA){
        float tlo = 0.f, thi = mx;
        for (int it = 0; it < 48; ++it){
            float th = 0.5f * (tlo + thi);
            float f = fmaxf(a0 - th, 0.f) + fmaxf(a1 - th, 0.f);
            for (int off = 32; off; off >>= 1) f += __shfl_xor(f, off);
            if (f > FKAPPA) tlo = th; else thi = th;
        }
        float th = 0.5f * (tlo + thi);
        w0 = copysignf(fmaxf(a0 - th, 0.f), w0);
        w1 = copysignf(fmaxf(a1 - th, 0.f), w1);
    }
    Wp[row * MDIM + l] = f2bf(w0);
    Wp[row * MDIM + l + 64] = f2bf(w1);
}

__global__ void k_cvt(const float* __restrict__ src, ushort* __restrict__ dst){
    int i = blockIdx.x * 256 + threadIdx.x;
    if (i < MDIM * MDIM) dst[i] = f2bf(src[i]);
}

// ---------------- transposes f32 [128][N] <-> bf16 [N][128] ----------------
__global__ void k_tin(const float* __restrict__ X0, const float* __restrict__ U,
                      ushort* __restrict__ Xt, ushort* __restrict__ Ut){
    __shared__ ushort tile[128 * 66];
    const float* src = blockIdx.y ? U : X0;
    ushort* dst = blockIdx.y ? Ut : Xt;
    int c0 = blockIdx.x * 64;
    int t = threadIdx.x;
    for (int it = 0; it < 32; ++it){
        int le = it * 256 + t;
        int j = le & 63, m = le >> 6;
        int c = c0 + j;
        tile[m * 66 + j] = (c < NCOL) ? f2bf(src[m * NCOL + c]) : (ushort)0;
    }
    __syncthreads();
    for (int it = 0; it < 32; ++it){
        int le = it * 256 + t;
        int m = le & 127, jc = le >> 7;
        int c = c0 + jc;
        if (c < NCOL) dst[c * MDIM + m] = tile[m * 66 + jc];
    }
}

__global__ void k_tout(const ushort* __restrict__ Xt, float* __restrict__ out){
    __shared__ ushort tile[128 * 66];
    int c0 = blockIdx.x * 64;
    int t = threadIdx.x;
    for (int it = 0; it < 32; ++it){
        int le = it * 256 + t;
        int m = le & 127, jc = le >> 7;
        int c = c0 + jc;
        tile[m * 66 + jc] = (c < NCOL) ? Xt[c * MDIM + m] : (ushort)0;
    }
    __syncthreads();
    for (int it = 0; it < 32; ++it){
        int le = it * 256 + t;
        int j = le & 63, m = le >> 6;
        int c = c0 + j;
        if (c < NCOL) out[m * NCOL + c] = bf2f(tile[m * 66 + j]);
    }
}

__device__ __forceinline__ void fma8(float* acc, uint4 x, float v){
    acc[0] += v * bf2f((ushort)(x.x & 0xffffu)); acc[1] += v * bf2f((ushort)(x.x >> 16));
    acc[2] += v * bf2f((ushort)(x.y & 0xffffu)); acc[3] += v * bf2f((ushort)(x.y >> 16));
    acc[4] += v * bf2f((ushort)(x.z & 0xffffu)); acc[5] += v * bf2f((ushort)(x.z >> 16));
    acc[6] += v * bf2f((ushort)(x.w & 0xffffu)); acc[7] += v * bf2f((ushort)(x.w >> 16));
}

// ---------------- Bt setup kernel (one shot): BtBF[c][m] = ((Om@U)@A)^T ------
__global__ __launch_bounds__(256, 4) void k_bt(const ushort* __restrict__ Xt_in,
                        const ushort* __restrict__ Mat,
                        ushort* __restrict__ outp,
                        const int* __restrict__ start,
                        const uint2* __restrict__ edges){
    __shared__ alignas(16) char GL[4 * 1024];
    int t = threadIdx.x;
    int w = t >> 6, l = t & 63;
    int c0 = blockIdx.x * 16;
    int g = l >> 4, sub = l & 15;

    int sa[5];
    #pragma unroll
    for (int i = 0; i < 5; ++i) sa[i] = start[c0 + w * 4 + i];
    uint2 myv[4];
    #pragma unroll
    for (int jj = 0; jj < 4; ++jj){
        int s = sa[jj], e = sa[jj + 1];
        int idx = (e > s) ? min(s + l, e - 1) : 0;
        myv[jj] = edges[idx];
    }
    #pragma unroll
    for (int jj = 0; jj < 4; ++jj){
        int s = sa[jj], e = sa[jj + 1];
        int d = e - s;
        float acc[8] = {0.f,0.f,0.f,0.f,0.f,0.f,0.f,0.f};
        if (d > 0){
            uint2 my = myv[jj];
            int r[8]; float v[8];
            #pragma unroll
            for (int b = 0; b < 8; ++b){
                int slot = b * 4 + g;
                int sel = min(slot, min(d, 64) - 1);
                r[b] = __shfl((int)my.x, sel);
                float vt = __builtin_bit_cast(float, __shfl((int)my.y, sel));
                v[b] = (slot < d) ? vt : 0.f;
            }
            uint4 x[8];
            #pragma unroll
            for (int b = 0; b < 8; ++b)
                x[b] = *(const uint4*)(Xt_in + (size_t)(uint)r[b] * 128 + sub * 8);
            #pragma unroll
            for (int b = 0; b < 8; ++b) fma8(acc, x[b], v[b]);
            if (d > 32){
                for (int k2 = s + 32; k2 < e; k2 += 4){
                    int ke = k2 + g;
                    uint2 p = edges[min(ke, e - 1)];
                    float vv = (ke < e) ? __builtin_bit_cast(float, p.y) : 0.f;
                    uint4 xx = *(const uint4*)(Xt_in + (size_t)p.x * 128 + sub * 8);
                    fma8(acc, xx, vv);
                }
            }
        }
        #pragma unroll
        for (int i = 0; i < 8; ++i){
            acc[i] += __shfl_xor(acc[i], 16);
            acc[i] += __shfl_xor(acc[i], 32);
        }
        int j = w * 4 + jj;
        if (l < 16){
            uint4 pk;
            pk.x = (uint)f2bf(acc[0]) | ((uint)f2bf(acc[1]) << 16);
            pk.y = (uint)f2bf(acc[2]) | ((uint)f2bf(acc[3]) << 16);
            pk.z = (uint)f2bf(acc[4]) | ((uint)f2bf(acc[5]) << 16);
            pk.w = (uint)f2bf(acc[6]) | ((uint)f2bf(acc[7]) << 16);
            *(uint4*)(GL + ((j * 256 + sub * 16) ^ ((j & 7) << 4))) = pk;
        }
    }
    __builtin_amdgcn_sched_barrier(0);
    short8 bfr[2][4];
    #pragma unroll
    for (int mt = 0; mt < 2; ++mt){
        int m = w * 32 + mt * 16 + (l & 15);
        #pragma unroll
        for (int kc = 0; kc < 4; ++kc)
            bfr[mt][kc] = *(const short8*)(Mat + m * MDIM + kc * 32 + (l >> 4) * 8);
    }
    __syncthreads();
    {
        int arow = l & 15;
        int klane = (l >> 4) * 16;
        int asw = (arow & 7) << 4;
        short8 afr[4];
        #pragma unroll
        for (int kc = 0; kc < 4; ++kc)
            afr[kc] = *(const short8*)(GL + ((arow * 256 + kc * 64 + klane) ^ asw));
        #pragma unroll
        for (int mt = 0; mt < 2; ++mt){
            int m = w * 32 + mt * 16 + (l & 15);
            f32x4 acc4 = {0.f, 0.f, 0.f, 0.f};
            #pragma unroll
            for (int kc = 0; kc < 4; ++kc)
                acc4 = __builtin_amdgcn_mfma_f32_16x16x32_bf16(afr[kc], bfr[mt][kc], acc4, 0, 0, 0);
            int crow_base = c0 + ((l >> 4) << 2);
            #pragma unroll
            for (int q = 0; q < 4; ++q)
                outp[(crow_base + q) * MDIM + m] = f2bf(acc4[q]);
        }
    }
}

// ---------------- device-scope grid barrier (generation counter) ----------
__device__ __forceinline__ void gbar(int* cnt, int* gen){
    __syncthreads();
    if (threadIdx.x == 0){
        __threadfence();
        int g = __hip_atomic_load(gen, __ATOMIC_RELAXED, __HIP_MEMORY_SCOPE_AGENT);
        int a = __hip_atomic_fetch_add(cnt, 1, __ATOMIC_ACQ_REL, __HIP_MEMORY_SCOPE_AGENT);
        if (a == NBLK - 1){
            __hip_atomic_store(cnt, 0, __ATOMIC_RELAXED, __HIP_MEMORY_SCOPE_AGENT);
            __hip_atomic_store(gen, g + 1, __ATOMIC_RELEASE, __HIP_MEMORY_SCOPE_AGENT);
        } else {
            while (__hip_atomic_load(gen, __ATOMIC_ACQUIRE, __HIP_MEMORY_SCOPE_AGENT) == g){
                __builtin_amdgcn_s_sleep(8);
            }
        }
    }
    __threadfence();
    __syncthreads();
}

// ---------------- persistent fixed-point iteration kernel ----------------
// 625 blocks x 256 thr (4 blocks/CU enforced -> all co-resident), 32 cols/block.
// Held across all 30 iterations: edge descriptors (VGPR), start (SGPR),
// Mat B-panel (VGPR), Bt epilogue values (16 regs/thread).
__global__ __launch_bounds__(256, 4) void k_persist(
        ushort* __restrict__ P0, ushort* __restrict__ P1,
        const ushort* __restrict__ Mat, const ushort* __restrict__ BtBF,
        const int* __restrict__ start, const uint2* __restrict__ edges,
        int* __restrict__ bar){
    __shared__ alignas(16) char GL[8 * 1024];     // G[32][128] bf16, swizzled
    int t = threadIdx.x;
    int w = t >> 6, l = t & 63;
    int c0 = blockIdx.x * 32;
    int g = l >> 4, sub = l & 15;

    // per-wave descriptors, once (static across iterations)
    int sa[9];
    #pragma unroll
    for (int i = 0; i < 9; ++i) sa[i] = start[c0 + w * 8 + i];
    uint2 myv[8];
    #pragma unroll
    for (int jj = 0; jj < 8; ++jj){
        int s = sa[jj], e = sa[jj + 1];
        int idx = (e > s) ? min(s + l, e - 1) : 0;
        myv[jj] = edges[idx];
    }

    // Mat B-panel once: rows [w*32, w*32+32)
    short8 bfr[2][4];
    #pragma unroll
    for (int mt = 0; mt < 2; ++mt){
        int m = w * 32 + mt * 16 + (l & 15);
        #pragma unroll
        for (int kc = 0; kc < 4; ++kc)
            bfr[mt][kc] = *(const short8*)(Mat + m * MDIM + kc * 32 + (l >> 4) * 8);
    }

    // Bt epilogue values once: 16 regs/thread
    float btv[2][2][4];
    #pragma unroll
    for (int cw = 0; cw < 2; ++cw){
        #pragma unroll
        for (int mt = 0; mt < 2; ++mt){
            int m = w * 32 + mt * 16 + (l & 15);
            #pragma unroll
            for (int q = 0; q < 4; ++q){
                int cl = cw * 16 + ((l >> 4) << 2) + q;
                btv[cw][mt][q] = bf2f(BtBF[(size_t)(c0 + cl) * 128 + m]);
            }
        }
    }

    ushort* cur = P0;
    ushort* nxt = P1;

#define ISSUE(X, V, col, half) do { \
    int d_ = sa[(col) + 1] - sa[(col)]; \
    uint2 my_ = myv[(col)]; \
    _Pragma("unroll") \
    for (int b = 0; b < 4; ++b){ \
        int slot_ = (half) * 16 + b * 4 + g; \
        int sel_ = min(slot_, max(d_ - 1, 0)); \
        int r_ = __shfl((int)my_.x, sel_); \
        float vt_ = __builtin_bit_cast(float, __shfl((int)my_.y, sel_)); \
        V[b] = (slot_ < d_) ? vt_ : 0.f; \
        X[b] = *(const uint4*)(cur + (size_t)(uint)r_ * 128 + sub * 8); \
    } } while (0)

    for (int it = 0; it < NITER; ++it){
        // ---------- gather: 8 cols/wave, 2 quads/col, 2-deep pipeline ----------
        {
            uint4 xa[4], xb[4];
            float va[4], vb[4];
            ISSUE(xa, va, 0, 0);
            #pragma unroll
            for (int col = 0; col < 8; ++col){
                float acc[8] = {0.f,0.f,0.f,0.f,0.f,0.f,0.f,0.f};
                ISSUE(xb, vb, col, 1);
                #pragma unroll
                for (int b = 0; b < 4; ++b) fma8(acc, xa[b], va[b]);
                if (col < 7) ISSUE(xa, va, col + 1, 0);
                #pragma unroll
                for (int b = 0; b < 4; ++b) fma8(acc, xb[b], vb[b]);
                // rare: degree > 32
                int s = sa[col], e = sa[col + 1], d = e - s;
                if (d > 32){
                    for (int k2 = s + 32; k2 < e; k2 += 4){
                        int ke = k2 + g;
                        uint2 p = edges[min(ke, e - 1)];
                        float vv = (ke < e) ? __builtin_bit_cast(float, p.y) : 0.f;
                        uint4 xx = *(const uint4*)(cur + (size_t)p.x * 128 + sub * 8);
                        fma8(acc, xx, vv);
                    }
                }
                #pragma unroll
                for (int i = 0; i < 8; ++i){
                    acc[i] += __shfl_xor(acc[i], 16);
                    acc[i] += __shfl_xor(acc[i], 32);
                }
                int j = w * 8 + col;
                if (l < 16){
                    uint4 pk;
                    pk.x = (uint)f2bf(acc[0]) | ((uint)f2bf(acc[1]) << 16);
                    pk.y = (uint)f2bf(acc[2]) | ((uint)f2bf(acc[3]) << 16);
                    pk.z = (uint)f2bf(acc[4]) | ((uint)f2bf(acc[5]) << 16);
                    pk.w = (uint)f2bf(acc[6]) | ((uint)f2bf(acc[7]) << 16);
                    *(uint4*)(GL + ((j * 256 + sub * 16) ^ ((j & 7) << 4))) = pk;
                }
            }
        }
        __syncthreads();

        // ---------- GEMM + bias + relu -> nxt ----------
        {
            int klane = (l >> 4) * 16;
            short8 afr[2][4];
            #pragma unroll
            for (int cw = 0; cw < 2; ++cw){
                int arow = cw * 16 + (l & 15);
                int asw = (arow & 7) << 4;
                #pragma unroll
                for (int kc = 0; kc < 4; ++kc)
                    afr[cw][kc] = *(const short8*)(GL + ((arow * 256 + kc * 64 + klane) ^ asw));
            }
            #pragma unroll
            for (int cw = 0; cw < 2; ++cw){
                #pragma unroll
                for (int mt = 0; mt < 2; ++mt){
                    int m = w * 32 + mt * 16 + (l & 15);
                    f32x4 a4 = {0.f, 0.f, 0.f, 0.f};
                    #pragma unroll
                    for (int kc = 0; kc < 4; ++kc)
                        a4 = __builtin_amdgcn_mfma_f32_16x16x32_bf16(afr[cw][kc], bfr[mt][kc], a4, 0, 0, 0);
                    int cl_base = cw * 16 + ((l >> 4) << 2);
                    #pragma unroll
                    for (int q = 0; q < 4; ++q){
                        int cl = cl_base + q;
                        float val = fmaxf(a4[q] + btv[cw][mt][q], 0.f);
                        nxt[(size_t)(c0 + cl) * 128 + m] = f2bf(val);
                    }
                }
            }
        }
        gbar(bar, bar + 1);
        ushort* tmp = cur; cur = nxt; nxt = tmp;
    }
#undef ISSUE
}

extern "C" void kernel_launch(void* const* d_in, const int* in_sizes, int n_in,
                              void* d_out, int out_size, void* d_ws, size_t ws_size,
                              hipStream_t stream){
    const float* X0 = (const float*)d_in[0];
    const float* U  = (const float*)d_in[1];
    const float* W  = (const float*)d_in[2];
    const float* Om = (const float*)d_in[3];
    const float* Av = (const float*)d_in[4];
    const int*   Ar = (const int*)d_in[5];
    const int*   Ac = (const int*)d_in[6];
    (void)in_sizes; (void)n_in; (void)out_size; (void)ws_size;

    char* ws = (char*)d_ws;
    size_t off = 0;
    auto alloc = [&](size_t bytes) -> char* {
        char* p = ws + off;
        off += (bytes + 255) & ~(size_t)255;
        return p;
    };
    int*    start = (int*)alloc((NCOL + 1) * 4);        //  80 KB
    uint2*  edges = (uint2*)alloc(NEDGE * 8);           //  2.56 MB
    ushort* Wp    = (ushort*)alloc(MDIM * MDIM * 2);    //  32 KB
    ushort* Omb   = (ushort*)alloc(MDIM * MDIM * 2);    //  32 KB
    int*    bar   = (int*)alloc(256);                   //  barrier state
    ushort* P0    = (ushort*)alloc(NCOL * MDIM * 2);    //  5.12 MB

    // cnt/cursor live in P0's space (dead before k_tin writes it)
    int* cnt    = (int*)P0;
    int* cursor = cnt + NCOL;

    // d_out (10.24 MB f32) hosts P1 + BtBF until the final transpose
    ushort* P1   = (ushort*)d_out;
    ushort* BtBF = (ushort*)((char*)d_out + NCOL * MDIM * 2);

    k_zero<<<(2 * NCOL + 255) / 256, 256, 0, stream>>>(cnt, bar);
    k_hist<<<(NEDGE + 255) / 256, 256, 0, stream>>>(Ac, cnt);
    k_scan<<<1, 256, 0, stream>>>(cnt, start);
    k_scatter<<<(NEDGE + 255) / 256, 256, 0, stream>>>(Ar, Ac, Av, start, cursor, edges);
    k_project<<<32, 256, 0, stream>>>(W, Wp);
    k_cvt<<<64, 256, 0, stream>>>(Om, Omb);
    k_tin<<<dim3(313, 2), 256, 0, stream>>>(X0, U, P0, P1);
    // BtBF = ((Omega_1 @ U) @ A)^T  (Ut lives in P1, dead afterwards)
    k_bt<<<1250, 256, 0, stream>>>(P1, Omb, BtBF, start, edges);

    // persistent 30-iteration fixed point: P0 -> P1 -> ... (even count -> ends in P0)
    k_persist<<<NBLK, 256, 0, stream>>>(P0, P1, Wp, BtBF, start, edges, bar);

    k_tout<<<313, 256, 0, stream>>>(P0, (float*)d_out);
}

// Round 10
// 736.697 us; speedup vs baseline: 8.4293x; 8.4293x over previous
//
#include <hip/hip_runtime.h>

#define MDIM 128
#define NCOL 20000
#define NEDGE 320000
#define NITER 30
#define FKAPPA 0.99f

typedef unsigned int uint;
typedef unsigned short ushort;
typedef __attribute__((ext_vector_type(8))) short short8;
typedef __attribute__((ext_vector_type(4))) float f32x4;

__device__ __forceinline__ float bf2f(ushort b){
    uint u = ((uint)b) << 16;
    return __builtin_bit_cast(float, u);
}
__device__ __forceinline__ ushort f2bf(float f){
    uint u = __builtin_bit_cast(uint, f);
    uint r = (u + 0x7fffu + ((u >> 16) & 1u)) >> 16;
    return (ushort)r;
}

// ---------------- CSC build ----------------
__global__ void k_zero(int* __restrict__ p){
    int i = blockIdx.x * 256 + threadIdx.x;
    if (i < 2 * NCOL) p[i] = 0;
}

__global__ void k_hist(const int* __restrict__ cols, int* __restrict__ cnt){
    int e = blockIdx.x * 256 + threadIdx.x;
    if (e < NEDGE) atomicAdd(&cnt[cols[e]], 1);
}

__global__ void k_scan(const int* __restrict__ cnt, int* __restrict__ start){
    __shared__ int lds[256];
    const int SEG = (NCOL + 255) / 256; // 79
    int t = threadIdx.x;
    int lo = t * SEG;
    int hi = min(lo + SEG, NCOL);
    int s = 0;
    for (int i = lo; i < hi; ++i) s += cnt[i];
    lds[t] = s;
    __syncthreads();
    for (int off = 1; off < 256; off <<= 1){
        int v = (t >= off) ? lds[t - off] : 0;
        __syncthreads();
        lds[t] += v;
        __syncthreads();
    }
    int run = (t > 0) ? lds[t - 1] : 0;
    for (int i = lo; i < hi; ++i){ start[i] = run; run += cnt[i]; }
    if (hi == NCOL && lo < NCOL) start[NCOL] = run;
}

// edges[p] = { row, f32_bits(val) }
__global__ void k_scatter(const int* __restrict__ rows, const int* __restrict__ cols,
                          const float* __restrict__ vals, const int* __restrict__ start,
                          int* __restrict__ cursor, uint2* __restrict__ edges){
    int e = blockIdx.x * 256 + threadIdx.x;
    if (e < NEDGE){
        int c = cols[e];
        int p = start[c] + atomicAdd(&cursor[c], 1);
        edges[p] = make_uint2((uint)rows[e], __builtin_bit_cast(uint, vals[e]));
    }
}

// ---------------- L-inf projection of W ----------------
__global__ void k_project(const float* __restrict__ W, ushort* __restrict__ Wp){
    int row = blockIdx.x * 4 + (threadIdx.x >> 6);
    int l = threadIdx.x & 63;
    const float* wr = W + row * MDIM;
    float w0 = wr[l], w1 = wr[l + 64];
    float a0 = fabsf(w0), a1 = fabsf(w1);
    float s = a0 + a1, mx = fmaxf(a0, a1);
    for (int off = 32; off; off >>= 1){
        s += __shfl_xor(s, off);
        mx = fmaxf(mx, __shfl_xor(mx, off));
    }
    if (s > FKAPPA){
        float tlo = 0.f, thi = mx;
        for (int it = 0; it < 48; ++it){
            float th = 0.5f * (tlo + thi);
            float f = fmaxf(a0 - th, 0.f) + fmaxf(a1 - th, 0.f);
            for (int off = 32; off; off >>= 1) f += __shfl_xor(f, off);
            if (f > FKAPPA) tlo = th; else thi = th;
        }
        float th = 0.5f * (tlo + thi);
        w0 = copysignf(fmaxf(a0 - th, 0.f), w0);
        w1 = copysignf(fmaxf(a1 - th, 0.f), w1);
    }
    Wp[row * MDIM + l] = f2bf(w0);
    Wp[row * MDIM + l + 64] = f2bf(w1);
}

__global__ void k_cvt(const float* __restrict__ src, ushort* __restrict__ dst){
    int i = blockIdx.x * 256 + threadIdx.x;
    if (i < MDIM * MDIM) dst[i] = f2bf(src[i]);
}

// ---------------- transposes f32 [128][N] <-> bf16 [N][128] ----------------
__global__ void k_tin(const float* __restrict__ X0, const float* __restrict__ U,
                      ushort* __restrict__ Xt, ushort* __restrict__ Ut){
    __shared__ ushort tile[128 * 66];
    const float* src = blockIdx.y ? U : X0;
    ushort* dst = blockIdx.y ? Ut : Xt;
    int c0 = blockIdx.x * 64;
    int t = threadIdx.x;
    for (int it = 0; it < 32; ++it){
        int le = it * 256 + t;
        int j = le & 63, m = le >> 6;
        int c = c0 + j;
        tile[m * 66 + j] = (c < NCOL) ? f2bf(src[m * NCOL + c]) : (ushort)0;
    }
    __syncthreads();
    for (int it = 0; it < 32; ++it){
        int le = it * 256 + t;
        int m = le & 127, jc = le >> 7;
        int c = c0 + jc;
        if (c < NCOL) dst[c * MDIM + m] = tile[m * 66 + jc];
    }
}

__global__ void k_tout(const ushort* __restrict__ Xt, float* __restrict__ out){
    __shared__ ushort tile[128 * 66];
    int c0 = blockIdx.x * 64;
    int t = threadIdx.x;
    for (int it = 0; it < 32; ++it){
        int le = it * 256 + t;
        int m = le & 127, jc = le >> 7;
        int c = c0 + jc;
        tile[m * 66 + jc] = (c < NCOL) ? Xt[c * MDIM + m] : (ushort)0;
    }
    __syncthreads();
    for (int it = 0; it < 32; ++it){
        int le = it * 256 + t;
        int j = le & 63, m = le >> 6;
        int c = c0 + j;
        if (c < NCOL) out[m * NCOL + c] = bf2f(tile[m * 66 + j]);
    }
}

__device__ __forceinline__ void fma8(float* acc, uint4 x, float v){
    acc[0] += v * bf2f((ushort)(x.x & 0xffffu)); acc[1] += v * bf2f((ushort)(x.x >> 16));
    acc[2] += v * bf2f((ushort)(x.y & 0xffffu)); acc[3] += v * bf2f((ushort)(x.y >> 16));
    acc[4] += v * bf2f((ushort)(x.z & 0xffffu)); acc[5] += v * bf2f((ushort)(x.z >> 16));
    acc[6] += v * bf2f((ushort)(x.w & 0xffffu)); acc[7] += v * bf2f((ushort)(x.w >> 16));
}

// ---------------- fused iteration ----------------
// out[c][m] = phi( sum_k (X@A)^T[c][k] * Mat[m][k] + Bt[c][m] )
// 16 cols/block (1250 blocks), 4 waves, 4 cols/wave.
// Gather: rolling 2-column pipeline — next column's 8 straight-line loads
// (32 slots, clamped slots = L1-hit duplicates with v=0) are issued before
// the current column's FMAs -> up to 16 x dwordx4 in flight per wave.
// Bt prefetched into registers between gather and GEMM.
template<int MODE>
__global__ __launch_bounds__(256, 4) void k_fused(const ushort* __restrict__ Xt_in,
                        const ushort* __restrict__ Mat,
                        const ushort* __restrict__ Bt,
                        ushort* __restrict__ outp,
                        const int* __restrict__ start,
                        const uint2* __restrict__ edges){
    __shared__ alignas(16) char GL[4 * 1024];  // G[16][128] bf16, XOR-swizzled rows
    int t = threadIdx.x;
    int w = t >> 6, l = t & 63;
    int c0 = blockIdx.x * 16;
    int g = l >> 4;     // edge slot within group-of-4
    int sub = l & 15;   // 16B chunk within 256B row

    // start[] values for this wave's 4 columns (uniform -> SGPRs)
    int sa[5];
    #pragma unroll
    for (int i = 0; i < 5; ++i) sa[i] = start[c0 + w * 4 + i];

    // preload edge descriptor vectors for all 4 columns (4 loads in flight)
    uint2 myv[4];
    #pragma unroll
    for (int jj = 0; jj < 4; ++jj){
        int s = sa[jj], e = sa[jj + 1];
        int idx = (e > s) ? min(s + l, e - 1) : 0;
        myv[jj] = edges[idx];
    }

    // 8 loads for column `col` (32 slots; clamped slots re-load same row = L1 hit)
#define LOADS(X, col) do { \
    int d_ = sa[(col) + 1] - sa[(col)]; \
    uint rx_ = myv[(col)].x; \
    _Pragma("unroll") \
    for (int r = 0; r < 8; ++r){ \
        int sel_ = min(r * 4 + g, max(d_ - 1, 0)); \
        int row_ = __shfl((int)rx_, sel_); \
        X[r] = *(const uint4*)(Xt_in + (size_t)(uint)row_ * 128 + sub * 8); \
    } } while (0)

    // FMAs + reduce + GL-write for column `col` using loaded X
#define PROC(X, col) do { \
    int s_ = sa[(col)], e_ = sa[(col) + 1]; \
    int d_ = e_ - s_; \
    uint ry_ = myv[(col)].y; \
    float acc[8] = {0.f,0.f,0.f,0.f,0.f,0.f,0.f,0.f}; \
    _Pragma("unroll") \
    for (int r = 0; r < 8; ++r){ \
        int slot_ = r * 4 + g; \
        int sel_ = min(slot_, max(d_ - 1, 0)); \
        float v_ = __builtin_bit_cast(float, __shfl((int)ry_, sel_)); \
        v_ = (slot_ < d_) ? v_ : 0.f; \
        fma8(acc, X[r], v_); \
    } \
    if (d_ > 32){ \
        for (int k2 = s_ + 32; k2 < e_; k2 += 4){ \
            int ke_ = k2 + g; \
            uint2 p_ = edges[min(ke_, e_ - 1)]; \
            float vv_ = (ke_ < e_) ? __builtin_bit_cast(float, p_.y) : 0.f; \
            uint4 xx_ = *(const uint4*)(Xt_in + (size_t)p_.x * 128 + sub * 8); \
            fma8(acc, xx_, vv_); \
        } \
    } \
    _Pragma("unroll") \
    for (int i = 0; i < 8; ++i){ \
        acc[i] += __shfl_xor(acc[i], 16); \
        acc[i] += __shfl_xor(acc[i], 32); \
    } \
    int j_ = w * 4 + (col); \
    if (l < 16){ \
        uint4 pk_; \
        pk_.x = (uint)f2bf(acc[0]) | ((uint)f2bf(acc[1]) << 16); \
        pk_.y = (uint)f2bf(acc[2]) | ((uint)f2bf(acc[3]) << 16); \
        pk_.z = (uint)f2bf(acc[4]) | ((uint)f2bf(acc[5]) << 16); \
        pk_.w = (uint)f2bf(acc[6]) | ((uint)f2bf(acc[7]) << 16); \
        *(uint4*)(GL + ((j_ * 256 + sub * 16) ^ ((j_ & 7) << 4))) = pk_; \
    } } while (0)

    {
        uint4 xa[8], xb[8];
        LOADS(xa, 0);
        LOADS(xb, 1); PROC(xa, 0);
        LOADS(xa, 2); PROC(xb, 1);
        LOADS(xb, 3); PROC(xa, 2);
        PROC(xb, 3);
    }
#undef LOADS
#undef PROC

    // keep Mat/Bt loads out of the gather loop (register pressure)
    __builtin_amdgcn_sched_barrier(0);

    // Mat B-panel for this wave: rows [w*32, w*32+32)
    short8 bfr[2][4];
    #pragma unroll
    for (int mt = 0; mt < 2; ++mt){
        int m = w * 32 + mt * 16 + (l & 15);
        #pragma unroll
        for (int kc = 0; kc < 4; ++kc)
            bfr[mt][kc] = *(const short8*)(Mat + m * MDIM + kc * 32 + (l >> 4) * 8);
    }

    // Bt prefetch: 16 epilogue values/thread (latency hides under barrier+MFMA)
    float btv[2][2][4];
    if (MODE == 1){
        #pragma unroll
        for (int cw = 0; cw < 2; ++cw){
            #pragma unroll
            for (int mt = 0; mt < 2; ++mt){
                int m = w * 32 + mt * 16 + (l & 15);
                #pragma unroll
                for (int q = 0; q < 4; ++q){
                    int cl = cw * 8 + ((l >> 4) << 1) + (q >> 1);
                    // map below must match GEMM epilogue: c = c0+cw*16+((l>>4)<<2)+q
                    (void)cl;
                    btv[cw][mt][q] = bf2f(Bt[(size_t)(c0 + cw * 16 + ((l >> 4) << 2) + q) * MDIM + m]);
                }
            }
        }
    }
    __syncthreads();

    // GEMM phase: out[16 x 128] = G * Mat^T ; wave w owns m-range [w*32, w*32+32)
    {
        int arow = l & 15;
        int klane = (l >> 4) * 16;
        int asw = (arow & 7) << 4;
        short8 afr[4];
        #pragma unroll
        for (int kc = 0; kc < 4; ++kc)
            afr[kc] = *(const short8*)(GL + ((arow * 256 + kc * 64 + klane) ^ asw));
        #pragma unroll
        for (int mt = 0; mt < 2; ++mt){
            int m = w * 32 + mt * 16 + (l & 15);
            f32x4 acc4 = {0.f, 0.f, 0.f, 0.f};
            #pragma unroll
            for (int kc = 0; kc < 4; ++kc)
                acc4 = __builtin_amdgcn_mfma_f32_16x16x32_bf16(afr[kc], bfr[mt][kc], acc4, 0, 0, 0);
            int crow_base = c0 + ((l >> 4) << 2);
            #pragma unroll
            for (int q = 0; q < 4; ++q){
                int c = crow_base + q;
                float val = acc4[q];
                if (MODE == 1){
                    val = fmaxf(val + btv[0][mt][q], 0.f);
                }
                outp[c * MDIM + m] = f2bf(val);
            }
        }
    }
}

extern "C" void kernel_launch(void* const* d_in, const int* in_sizes, int n_in,
                              void* d_out, int out_size, void* d_ws, size_t ws_size,
                              hipStream_t stream){
    const float* X0 = (const float*)d_in[0];
    const float* U  = (const float*)d_in[1];
    const float* W  = (const float*)d_in[2];
    const float* Om = (const float*)d_in[3];
    const float* Av = (const float*)d_in[4];
    const int*   Ar = (const int*)d_in[5];
    const int*   Ac = (const int*)d_in[6];
    (void)in_sizes; (void)n_in; (void)out_size; (void)ws_size;

    char* ws = (char*)d_ws;
    size_t off = 0;
    auto alloc = [&](size_t bytes) -> char* {
        char* p = ws + off;
        off += (bytes + 255) & ~(size_t)255;
        return p;
    };
    int*    start = (int*)alloc((NCOL + 1) * 4);        //  80 KB
    uint2*  edges = (uint2*)alloc(NEDGE * 8);           //  2.56 MB
    ushort* Wp    = (ushort*)alloc(MDIM * MDIM * 2);    //  32 KB
    ushort* Omb   = (ushort*)alloc(MDIM * MDIM * 2);    //  32 KB
    ushort* P0    = (ushort*)alloc(NCOL * MDIM * 2);    //  5.12 MB

    // cnt/cursor live in P0's space (dead before k_tin writes it)
    int* cnt    = (int*)P0;
    int* cursor = cnt + NCOL;

    // d_out (10.24 MB f32) hosts P1 + Bt until the final transpose
    ushort* P1   = (ushort*)d_out;
    ushort* BtBF = (ushort*)((char*)d_out + NCOL * MDIM * 2);

    k_zero<<<(2 * NCOL + 255) / 256, 256, 0, stream>>>(cnt);
    k_hist<<<(NEDGE + 255) / 256, 256, 0, stream>>>(Ac, cnt);
    k_scan<<<1, 256, 0, stream>>>(cnt, start);
    k_scatter<<<(NEDGE + 255) / 256, 256, 0, stream>>>(Ar, Ac, Av, start, cursor, edges);
    k_project<<<32, 256, 0, stream>>>(W, Wp);
    k_cvt<<<64, 256, 0, stream>>>(Om, Omb);
    k_tin<<<dim3(313, 2), 256, 0, stream>>>(X0, U, P0, P1);
    // Bt = ((Omega_1 @ U) @ A)^T, stored bf16
    k_fused<0><<<1250, 256, 0, stream>>>(P1, Omb, nullptr, BtBF, start, edges);
    const ushort* cur = P0; ushort* nxt = P1;
    for (int i = 0; i < NITER; ++i){
        k_fused<1><<<1250, 256, 0, stream>>>(cur, Wp, BtBF, nxt, start, edges);
        ushort* tmp = (ushort*)cur; cur = nxt; nxt = tmp;
    }
    // NITER even -> cur == P0 (ws); k_tout overwrites all of d_out (P1/Bt dead)
    k_tout<<<313, 256, 0, stream>>>(cur, (float*)d_out);
}